// Round 25
// baseline (149.123 us; speedup 1.0000x reference)
//
#include <hip/hip_runtime.h>
#include <hip/hip_bf16.h>
#include <math.h>

typedef __attribute__((ext_vector_type(8))) short short8;
typedef __attribute__((ext_vector_type(4))) short short4v;
typedef __attribute__((ext_vector_type(4))) float f32x4;

#define LOG2E 1.44269504088896f

__device__ __forceinline__ unsigned short f2bf(float f) {
  union { float f; unsigned int u; } v; v.f = f;
  unsigned int r = v.u + 0x7fffu + ((v.u >> 16) & 1u);
  return (unsigned short)(r >> 16);
}
__device__ __forceinline__ float bf2f(unsigned short h) {
  union { unsigned int u; float f; } v; v.u = ((unsigned int)h) << 16;
  return v.f;
}

// ---------------- kernel 1: transpose Wq,Wk into wt[c][64] — byte-identical to round 24
__global__ void k_wtrans(const float* __restrict__ Wq, const float* __restrict__ Wk,
                         float* __restrict__ wt) {
  for (int i = threadIdx.x; i < 32 * 256; i += 256) {
    int d = i >> 8, c = i & 255;
    wt[c * 64 + d] = Wq[i];
    wt[c * 64 + 32 + d] = Wk[i];
  }
}

// ---------------- kernel 2: FUSED qkproj + caststyle — byte-identical to round 24 -----
__global__ __launch_bounds__(256) void k_projcast(
    const float* __restrict__ input, const float* __restrict__ structure,
    const float* __restrict__ wt, const float* __restrict__ bq, const float* __restrict__ bk,
    unsigned short* __restrict__ qh, unsigned short* __restrict__ ql,
    unsigned short* __restrict__ kh,
    const float* __restrict__ style, unsigned short* __restrict__ xsf) {
  __shared__ float red[2 * 64 * 65];   // 33,280 B (qkproj role only)
  const int id = blockIdx.x;
  if (id < 256) {
    // ======================= qkproj role =======================
    const int b = id >> 6;
    const int n0 = (id & 63) * 64;
    const int wu = __builtin_amdgcn_readfirstlane(threadIdx.x >> 6);  // c-quarter 0..3
    const int l = threadIdx.x & 63;
    const size_t ibase = ((size_t)b << 20) + (size_t)(n0 + l);

    float aq[32], ak[32];
#pragma unroll
    for (int d = 0; d < 32; ++d) { aq[d] = 0.f; ak[d] = 0.f; }

#pragma unroll 2
    for (int cc = 0; cc < 64; ++cc) {
      const int c = wu * 64 + cc;
      const float xq = input[ibase + ((size_t)c << 12)];
      const float xk = structure[ibase + ((size_t)c << 12)];
      const float* wr = wt + c * 64;   // uniform -> s_loads
#pragma unroll
      for (int d = 0; d < 32; ++d) {
        aq[d] = fmaf(wr[d], xq, aq[d]);
        ak[d] = fmaf(wr[32 + d], xk, ak[d]);
      }
    }
    float* myred = red + ((wu & 1) * 64 + l) * 65;
    if (wu < 2) {
#pragma unroll
      for (int d = 0; d < 32; ++d) { myred[d] = aq[d]; myred[32 + d] = ak[d]; }
    }
    __syncthreads();
    if (wu >= 2) {
#pragma unroll
      for (int d = 0; d < 32; ++d) { myred[d] += aq[d]; myred[32 + d] += ak[d]; }
    }
    __syncthreads();

    const int p = threadIdx.x & 63;
    const int half = (threadIdx.x >> 6) & 1;  // 0:q 1:k
    const int dh = threadIdx.x >> 7;          // d half
    const float* bias = half ? bk : bq;
    const float scl = half ? 1.0f : LOG2E;
    unsigned short hs[16], lo[16];
#pragma unroll
    for (int d2 = 0; d2 < 16; ++d2) {
      const int d = dh * 16 + d2;
      float v = red[p * 65 + half * 32 + d] + red[(64 + p) * 65 + half * 32 + d];
      v = (v + bias[d]) * scl;
      unsigned short h = f2bf(v);
      hs[d2] = h;
      lo[d2] = f2bf(v - bf2f(h));
    }
    const size_t row = ((size_t)b << 12) + (size_t)(n0 + p);
    if (!half) {
      unsigned short* dsth = qh + row * 32 + dh * 16;
      unsigned short* dstl = ql + row * 32 + dh * 16;
#pragma unroll
      for (int i2 = 0; i2 < 2; ++i2) {
        uint4 t, t2;
        t.x = (unsigned)hs[i2*8+0] | ((unsigned)hs[i2*8+1] << 16);
        t.y = (unsigned)hs[i2*8+2] | ((unsigned)hs[i2*8+3] << 16);
        t.z = (unsigned)hs[i2*8+4] | ((unsigned)hs[i2*8+5] << 16);
        t.w = (unsigned)hs[i2*8+6] | ((unsigned)hs[i2*8+7] << 16);
        t2.x = (unsigned)lo[i2*8+0] | ((unsigned)lo[i2*8+1] << 16);
        t2.y = (unsigned)lo[i2*8+2] | ((unsigned)lo[i2*8+3] << 16);
        t2.z = (unsigned)lo[i2*8+4] | ((unsigned)lo[i2*8+5] << 16);
        t2.w = (unsigned)lo[i2*8+6] | ((unsigned)lo[i2*8+7] << 16);
        ((uint4*)dsth)[i2] = t;
        ((uint4*)dstl)[i2] = t2;
      }
    } else {
      unsigned short* dsth = kh + row * 32 + dh * 16;
#pragma unroll
      for (int i2 = 0; i2 < 2; ++i2) {
        uint4 t;
        t.x = (unsigned)hs[i2*8+0] | ((unsigned)hs[i2*8+1] << 16);
        t.y = (unsigned)hs[i2*8+2] | ((unsigned)hs[i2*8+3] << 16);
        t.z = (unsigned)hs[i2*8+4] | ((unsigned)hs[i2*8+5] << 16);
        t.w = (unsigned)hs[i2*8+6] | ((unsigned)hs[i2*8+7] << 16);
        ((uint4*)dsth)[i2] = t;
      }
    }
  } else {
    // ======================= caststyle role =======================
    const int cid = id - 256;               // 0..255
    const int nb = cid & 15;
    const int ct = (cid >> 4) & 3;
    const int b = cid >> 6;
    const int n = nb * 256 + threadIdx.x;
    const float* src = style + ((size_t)b << 20) + (((size_t)(ct * 64)) << 12) + (size_t)n;
    const int ntile = n >> 4, m = n & 15;
#pragma unroll
    for (int gq = 0; gq < 8; ++gq) {
      uint4 t;
      unsigned vv[4];
#pragma unroll
      for (int q2 = 0; q2 < 4; ++q2) {
        unsigned short a = f2bf(src[((size_t)(gq * 8 + q2 * 2)) << 12]);
        unsigned short bb = f2bf(src[((size_t)(gq * 8 + q2 * 2 + 1)) << 12]);
        vv[q2] = (unsigned)a | ((unsigned)bb << 16);
      }
      t.x = vv[0]; t.y = vv[1]; t.z = vv[2]; t.w = vv[3];
      const int kc = ct * 2 + (gq >> 2);
      const int g = gq & 3;
      const size_t fa = ((((size_t)(b * 256 + ntile)) * 8 + kc) * 64 + g * 16 + m) * 8;
      *(uint4*)(xsf + fa) = t;
    }
  }
}

// ---------------- kernel 4: v = Wv @ style — byte-identical to round 24. grid (32,4,4).
__global__ __launch_bounds__(256) void k_vgemm(const unsigned short* __restrict__ xsf,
                                               const float* __restrict__ Wv,
                                               const float* __restrict__ bv,
                                               unsigned short* __restrict__ vws) {
  const int b = blockIdx.z, coT = blockIdx.y, nT = blockIdx.x;
  const int w = threadIdx.x >> 6, l = threadIdx.x & 63;
  const int m = l & 15, g = l >> 4;
  const int co0 = coT * 64 + w * 16;
  const int n0 = nT * 128;
  f32x4 acc[8];
#pragma unroll
  for (int f = 0; f < 8; ++f) { acc[f][0]=0.f; acc[f][1]=0.f; acc[f][2]=0.f; acc[f][3]=0.f; }

#pragma unroll 2
  for (int kc = 0; kc < 8; ++kc) {
    const int c0 = kc * 32 + g * 8;
    const float* wp = Wv + (size_t)(co0 + m) * 256 + c0;
    float4 a0 = *(const float4*)wp;
    float4 a1 = *(const float4*)(wp + 4);
    short8 af;
    af[0]=(short)f2bf(a0.x); af[1]=(short)f2bf(a0.y); af[2]=(short)f2bf(a0.z); af[3]=(short)f2bf(a0.w);
    af[4]=(short)f2bf(a1.x); af[5]=(short)f2bf(a1.y); af[6]=(short)f2bf(a1.z); af[7]=(short)f2bf(a1.w);
#pragma unroll
    for (int f = 0; f < 8; ++f) {
      const short8 bfr = *(const short8*)(xsf +
        ((((size_t)(b * 256 + (nT * 8 + f))) * 8 + kc) * 64 + l) * 8);
      acc[f] = __builtin_amdgcn_mfma_f32_16x16x32_bf16(af, bfr, acc[f], 0, 0, 0);
    }
  }
  float4 bvv = *(const float4*)(bv + co0 + g * 4);
  const float bvr[4] = {bvv.x, bvv.y, bvv.z, bvv.w};
#pragma unroll
  for (int f = 0; f < 8; ++f)
#pragma unroll
    for (int r = 0; r < 4; ++r) {
      const int co = co0 + g * 4 + r;
      const int n = n0 + f * 16 + m;
      vws[(((size_t)(b * 256 + co)) << 12) + n] = f2bf(acc[f][r] + bvr[r]);
    }
}

// ---------------- kernel 5: fused flash attention — r24 config + CROSS-ITERATION
// SOFTWARE PIPELINE: V/K for iter t+1 loaded right after barrier(t) (latency spans
// PV(t)+S(t+1)); permissive sched_barrier(0x38F) pins only VMEM (ALU/MFMA/DS free —
// unlike r16's full freeze). Rotation via register copies. Math identical.
#define P_PANEL  16384   // 128 rows x 128 B per panel, 2 panels per buffer
#define P_BUF    32768   // per-buffer P size
#define LDS_TOT  65536

__global__ __launch_bounds__(512, 2) void k_flash(
    const unsigned short* __restrict__ qh_ws, const unsigned short* __restrict__ ql_ws,
    const unsigned short* __restrict__ kh_ws, const unsigned short* __restrict__ v_ws,
    float* __restrict__ out0, unsigned short* __restrict__ pacc1,
    float* __restrict__ pl) {
  __shared__ char lds[LDS_TOT];
  const int bid = blockIdx.x;
  const int qt = bid >> 3;          // 0..31, 128 queries each
  const int b = (bid >> 1) & 3;
  const int jh = bid & 1;
  const int tid = threadIdx.x;
  const int w = __builtin_amdgcn_readfirstlane(tid >> 6);   // wave 0..7
  const int l = tid & 63;
  const int m = l & 15, g = l >> 4;

  const size_t qrow = (((size_t)b << 12) + (size_t)(qt * 128 + w * 16 + m)) * 32 + g * 8;
  const short8 qhf = *(const short8*)(qh_ws + qrow);
  const short8 qlf = *(const short8*)(ql_ws + qrow);

  f32x4 acc[8][2];
#pragma unroll
  for (int it = 0; it < 8; ++it)
#pragma unroll
    for (int ct = 0; ct < 2; ++ct) { acc[it][ct][0]=0.f; acc[it][ct][1]=0.f; acc[it][ct][2]=0.f; acc[it][ct][3]=0.f; }
  float lsum[4];
#pragma unroll
  for (int r = 0; r < 4; ++r) lsum[r] = 0.f;

  const int jbase = jh * 2048;
  // ---- prologue: load iter-0 V and K ----
  short8 vcur[4][2], kcur[8];
#pragma unroll
  for (int ks = 0; ks < 4; ++ks)
#pragma unroll
    for (int ct = 0; ct < 2; ++ct)
      vcur[ks][ct] = *(const short8*)(v_ws +
        (((size_t)(b * 256 + w * 32 + ct * 16 + m)) << 12) + jbase + ks * 32 + g * 8);
#pragma unroll
  for (int t = 0; t < 8; ++t)
    kcur[t] = *(const short8*)(kh_ws + (((size_t)b << 12) + (size_t)(jbase + t * 16 + m)) * 32 + g * 8);

  for (int jt = 0; jt < 16; ++jt) {
    const int pb = jt & 1;
    char* Pb = lds + pb * P_BUF;
    // ---- S phase from prefetched kcur ----
    f32x4 sv[8];
#pragma unroll
    for (int t = 0; t < 8; ++t) {
      f32x4 z = {0.f, 0.f, 0.f, 0.f};
      f32x4 s0 = __builtin_amdgcn_mfma_f32_16x16x32_bf16(qhf, kcur[t], z, 0, 0, 0);
      sv[t] = __builtin_amdgcn_mfma_f32_16x16x32_bf16(qlf, kcur[t], s0, 0, 0, 0);
    }
#pragma unroll
    for (int t = 0; t < 8; ++t)
#pragma unroll
      for (int r = 0; r < 4; ++r) {
        const float p = exp2f(sv[t][r]);
        lsum[r] += p;
        const int row = w * 16 + g * 4 + r;
        const int cw2 = (t & 3) * 32 + 2 * m;
        *(unsigned short*)(Pb + (t >> 2) * P_PANEL + row * 128 + (cw2 ^ ((row & 7) << 4))) = f2bf(p);
      }
    __syncthreads();   // the ONLY barrier: P[pb] ready
    // ---- prefetch NEXT tile: latency spans PV(t) + S(t+1). jt=15 wraps (discarded).
    const int jn = jbase + ((jt + 1) & 15) * 128;
    short8 vnxt[4][2], knxt[8];
#pragma unroll
    for (int ks = 0; ks < 4; ++ks)
#pragma unroll
      for (int ct = 0; ct < 2; ++ct)
        vnxt[ks][ct] = *(const short8*)(v_ws +
          (((size_t)(b * 256 + w * 32 + ct * 16 + m)) << 12) + jn + ks * 32 + g * 8);
#pragma unroll
    for (int t = 0; t < 8; ++t)
      knxt[t] = *(const short8*)(kh_ws + (((size_t)b << 12) + (size_t)(jn + t * 16 + m)) * 32 + g * 8);
    // VMEM may not be rescheduled across this point; ALU/SALU/MFMA/DS move freely.
    __builtin_amdgcn_sched_barrier(0x38F);
    // ---- PV from vcur (in registers since last iteration) ----
#pragma unroll
    for (int ks = 0; ks < 4; ++ks) {
      short8 pa[8];
#pragma unroll
      for (int it = 0; it < 8; ++it) {
        const int row = it * 16 + m;
        pa[it] = *(const short8*)(Pb + (ks >> 1) * P_PANEL + row * 128 +
                                  (((ks & 1) * 64 + g * 16) ^ ((row & 7) << 4)));
      }
#pragma unroll
      for (int ct = 0; ct < 2; ++ct)
#pragma unroll
        for (int it = 0; it < 8; ++it)
          acc[it][ct] = __builtin_amdgcn_mfma_f32_16x16x32_bf16(pa[it], vcur[ks][ct], acc[it][ct], 0, 0, 0);
    }
    // ---- rotate pipeline registers ----
#pragma unroll
    for (int ks = 0; ks < 4; ++ks) { vcur[ks][0] = vnxt[ks][0]; vcur[ks][1] = vnxt[ks][1]; }
#pragma unroll
    for (int t = 0; t < 8; ++t) kcur[t] = knxt[t];
    // no barrier B: next iter writes the OTHER P buffer (r14 safety argument)
  }
#pragma unroll
  for (int d = 1; d <= 8; d <<= 1)
#pragma unroll
    for (int r = 0; r < 4; ++r) lsum[r] += __shfl_xor(lsum[r], d);
  if (m == 0) {
#pragma unroll
    for (int r = 0; r < 4; ++r) {
      const int row = qt * 128 + w * 16 + g * 4 + r;
      pl[(size_t)jh * 16384 + ((size_t)b << 12) + row] = lsum[r];
    }
  }
  if (jh == 0) {
#pragma unroll
    for (int it = 0; it < 8; ++it)
#pragma unroll
      for (int ct = 0; ct < 2; ++ct) {
        const int c = w * 32 + ct * 16 + m;
        float4 o;
        o.x = acc[it][ct][0]; o.y = acc[it][ct][1]; o.z = acc[it][ct][2]; o.w = acc[it][ct][3];
        *(float4*)(out0 + (((size_t)(b * 256 + c)) << 12) + qt * 128 + it * 16 + g * 4) = o;
      }
  } else {
#pragma unroll
    for (int it = 0; it < 8; ++it)
#pragma unroll
      for (int ct = 0; ct < 2; ++ct) {
        const int c = w * 32 + ct * 16 + m;
        short4v o;
        o[0] = (short)f2bf(acc[it][ct][0]); o[1] = (short)f2bf(acc[it][ct][1]);
        o[2] = (short)f2bf(acc[it][ct][2]); o[3] = (short)f2bf(acc[it][ct][3]);
        *(short4v*)(pacc1 + (((size_t)(b * 256 + c)) << 12) + qt * 128 + it * 16 + g * 4) = o;
      }
  }
}

// ---------------- kernel 6: combine the two j-halves — byte-identical to round 24 -----
__global__ __launch_bounds__(256) void k_combine(float* o, const unsigned short* __restrict__ pacc1,
                                                 const float* __restrict__ pl) {
  const int b = blockIdx.y;
  const int n = blockIdx.x * 64 + (threadIdx.x & 63);
  const int c0 = (threadIdx.x >> 6) * 64;
  const size_t mi = ((size_t)b << 12) + n;
  const float rl = 1.0f / (pl[mi] + pl[16384 + mi]);
#pragma unroll 4
  for (int ci = 0; ci < 64; ++ci) {
    const size_t a = (((size_t)(b * 256 + c0 + ci)) << 12) + n;
    o[a] = (o[a] + bf2f(pacc1[a])) * rl;
  }
}

// ---------------- launch ----------------
extern "C" void kernel_launch(void* const* d_in, const int* in_sizes, int n_in,
                              void* d_out, int out_size, void* d_ws, size_t ws_size,
                              hipStream_t stream) {
  (void)in_sizes; (void)n_in; (void)out_size; (void)ws_size;
  const float* input     = (const float*)d_in[0];
  const float* structure = (const float*)d_in[1];
  const float* style     = (const float*)d_in[2];
  const float* Wq = (const float*)d_in[3];
  const float* bq = (const float*)d_in[4];
  const float* Wk = (const float*)d_in[5];
  const float* bk = (const float*)d_in[6];
  const float* Wv = (const float*)d_in[7];
  const float* bv = (const float*)d_in[8];
  float* out = (float*)d_out;
  char* ws = (char*)d_ws;

  // ws layout — proven extents: total 20,250,624 B
  float* wt           = (float*)(ws);
  unsigned short* qh  = (unsigned short*)(ws + 65536);
  unsigned short* ql  = (unsigned short*)(ws + 65536 + 1048576);
  unsigned short* kh  = (unsigned short*)(ws + 65536 + 2097152);
  unsigned short* vw  = (unsigned short*)(ws + 65536 + 3145728);               // row-major V
  unsigned short* xsf = (unsigned short*)(ws + 65536 + 3145728 + 8388608);     // fragment-order
  unsigned short* pacc1 = xsf;  // aliases xsf (dead after k_vgemm; stream-ordered)
  float* pl           = (float*)(ws + 20119552);

  k_wtrans<<<dim3(1), dim3(256), 0, stream>>>(Wq, Wk, wt);
  k_projcast<<<dim3(512), dim3(256), 0, stream>>>(input, structure, wt, bq, bk,
                                                  qh, ql, kh, style, xsf);
  k_vgemm<<<dim3(32, 4, 4), dim3(256), 0, stream>>>(xsf, Wv, bv, vw);
  k_flash<<<dim3(256), dim3(512), 0, stream>>>(qh, ql, kh, vw, out, pacc1, pl);
  k_combine<<<dim3(64, 4), dim3(256), 0, stream>>>(out, pacc1, pl);
}

// Round 26
// 140.272 us; speedup vs baseline: 1.0631x; 1.0631x over previous
//
#include <hip/hip_runtime.h>
#include <hip/hip_bf16.h>
#include <math.h>

typedef __attribute__((ext_vector_type(8))) short short8;
typedef __attribute__((ext_vector_type(4))) short short4v;
typedef __attribute__((ext_vector_type(4))) float f32x4;

#define LOG2E 1.44269504088896f

__device__ __forceinline__ unsigned short f2bf(float f) {
  union { float f; unsigned int u; } v; v.f = f;
  unsigned int r = v.u + 0x7fffu + ((v.u >> 16) & 1u);
  return (unsigned short)(r >> 16);
}
__device__ __forceinline__ float bf2f(unsigned short h) {
  union { unsigned int u; float f; } v; v.u = ((unsigned int)h) << 16;
  return v.f;
}

// ---------------- kernel 1: transpose Wq,Wk into wt[c][64] ----------------------------
__global__ void k_wtrans(const float* __restrict__ Wq, const float* __restrict__ Wk,
                         float* __restrict__ wt) {
  for (int i = threadIdx.x; i < 32 * 256; i += 256) {
    int d = i >> 8, c = i & 255;
    wt[c * 64 + d] = Wq[i];
    wt[c * 64 + 32 + d] = Wk[i];
  }
}

// ---------------- kernel 2: FUSED qkproj + caststyle (round-24 proven) ----------------
__global__ __launch_bounds__(256) void k_projcast(
    const float* __restrict__ input, const float* __restrict__ structure,
    const float* __restrict__ wt, const float* __restrict__ bq, const float* __restrict__ bk,
    unsigned short* __restrict__ qh, unsigned short* __restrict__ ql,
    unsigned short* __restrict__ kh,
    const float* __restrict__ style, unsigned short* __restrict__ xsf) {
  __shared__ float red[2 * 64 * 65];   // 33,280 B (qkproj role only)
  const int id = blockIdx.x;
  if (id < 256) {
    // ======================= qkproj role =======================
    const int b = id >> 6;
    const int n0 = (id & 63) * 64;
    const int wu = __builtin_amdgcn_readfirstlane(threadIdx.x >> 6);  // c-quarter 0..3
    const int l = threadIdx.x & 63;
    const size_t ibase = ((size_t)b << 20) + (size_t)(n0 + l);

    float aq[32], ak[32];
#pragma unroll
    for (int d = 0; d < 32; ++d) { aq[d] = 0.f; ak[d] = 0.f; }

#pragma unroll 2
    for (int cc = 0; cc < 64; ++cc) {
      const int c = wu * 64 + cc;
      const float xq = input[ibase + ((size_t)c << 12)];
      const float xk = structure[ibase + ((size_t)c << 12)];
      const float* wr = wt + c * 64;   // uniform -> s_loads
#pragma unroll
      for (int d = 0; d < 32; ++d) {
        aq[d] = fmaf(wr[d], xq, aq[d]);
        ak[d] = fmaf(wr[32 + d], xk, ak[d]);
      }
    }
    float* myred = red + ((wu & 1) * 64 + l) * 65;
    if (wu < 2) {
#pragma unroll
      for (int d = 0; d < 32; ++d) { myred[d] = aq[d]; myred[32 + d] = ak[d]; }
    }
    __syncthreads();
    if (wu >= 2) {
#pragma unroll
      for (int d = 0; d < 32; ++d) { myred[d] += aq[d]; myred[32 + d] += ak[d]; }
    }
    __syncthreads();

    const int p = threadIdx.x & 63;
    const int half = (threadIdx.x >> 6) & 1;  // 0:q 1:k
    const int dh = threadIdx.x >> 7;          // d half
    const float* bias = half ? bk : bq;
    const float scl = half ? 1.0f : LOG2E;
    unsigned short hs[16], lo[16];
#pragma unroll
    for (int d2 = 0; d2 < 16; ++d2) {
      const int d = dh * 16 + d2;
      float v = red[p * 65 + half * 32 + d] + red[(64 + p) * 65 + half * 32 + d];
      v = (v + bias[d]) * scl;
      unsigned short h = f2bf(v);
      hs[d2] = h;
      lo[d2] = f2bf(v - bf2f(h));
    }
    const size_t row = ((size_t)b << 12) + (size_t)(n0 + p);
    if (!half) {
      unsigned short* dsth = qh + row * 32 + dh * 16;
      unsigned short* dstl = ql + row * 32 + dh * 16;
#pragma unroll
      for (int i2 = 0; i2 < 2; ++i2) {
        uint4 t, t2;
        t.x = (unsigned)hs[i2*8+0] | ((unsigned)hs[i2*8+1] << 16);
        t.y = (unsigned)hs[i2*8+2] | ((unsigned)hs[i2*8+3] << 16);
        t.z = (unsigned)hs[i2*8+4] | ((unsigned)hs[i2*8+5] << 16);
        t.w = (unsigned)hs[i2*8+6] | ((unsigned)hs[i2*8+7] << 16);
        t2.x = (unsigned)lo[i2*8+0] | ((unsigned)lo[i2*8+1] << 16);
        t2.y = (unsigned)lo[i2*8+2] | ((unsigned)lo[i2*8+3] << 16);
        t2.z = (unsigned)lo[i2*8+4] | ((unsigned)lo[i2*8+5] << 16);
        t2.w = (unsigned)lo[i2*8+6] | ((unsigned)lo[i2*8+7] << 16);
        ((uint4*)dsth)[i2] = t;
        ((uint4*)dstl)[i2] = t2;
      }
    } else {
      unsigned short* dsth = kh + row * 32 + dh * 16;
#pragma unroll
      for (int i2 = 0; i2 < 2; ++i2) {
        uint4 t;
        t.x = (unsigned)hs[i2*8+0] | ((unsigned)hs[i2*8+1] << 16);
        t.y = (unsigned)hs[i2*8+2] | ((unsigned)hs[i2*8+3] << 16);
        t.z = (unsigned)hs[i2*8+4] | ((unsigned)hs[i2*8+5] << 16);
        t.w = (unsigned)hs[i2*8+6] | ((unsigned)hs[i2*8+7] << 16);
        ((uint4*)dsth)[i2] = t;
      }
    }
  } else {
    // ======================= caststyle role =======================
    const int cid = id - 256;               // 0..255
    const int nb = cid & 15;
    const int ct = (cid >> 4) & 3;
    const int b = cid >> 6;
    const int n = nb * 256 + threadIdx.x;
    const float* src = style + ((size_t)b << 20) + (((size_t)(ct * 64)) << 12) + (size_t)n;
    const int ntile = n >> 4, m = n & 15;
#pragma unroll
    for (int gq = 0; gq < 8; ++gq) {
      uint4 t;
      unsigned vv[4];
#pragma unroll
      for (int q2 = 0; q2 < 4; ++q2) {
        unsigned short a = f2bf(src[((size_t)(gq * 8 + q2 * 2)) << 12]);
        unsigned short bb = f2bf(src[((size_t)(gq * 8 + q2 * 2 + 1)) << 12]);
        vv[q2] = (unsigned)a | ((unsigned)bb << 16);
      }
      t.x = vv[0]; t.y = vv[1]; t.z = vv[2]; t.w = vv[3];
      const int kc = ct * 2 + (gq >> 2);
      const int g = gq & 3;
      const size_t fa = ((((size_t)(b * 256 + ntile)) * 8 + kc) * 64 + g * 16 + m) * 8;
      *(uint4*)(xsf + fa) = t;
    }
  }
}

// ---------------- kernel 4: v = Wv @ style (fragment-ordered B reads). grid (32,4,4). -
__global__ __launch_bounds__(256) void k_vgemm(const unsigned short* __restrict__ xsf,
                                               const float* __restrict__ Wv,
                                               const float* __restrict__ bv,
                                               unsigned short* __restrict__ vws) {
  const int b = blockIdx.z, coT = blockIdx.y, nT = blockIdx.x;
  const int w = threadIdx.x >> 6, l = threadIdx.x & 63;
  const int m = l & 15, g = l >> 4;
  const int co0 = coT * 64 + w * 16;
  const int n0 = nT * 128;
  f32x4 acc[8];
#pragma unroll
  for (int f = 0; f < 8; ++f) { acc[f][0]=0.f; acc[f][1]=0.f; acc[f][2]=0.f; acc[f][3]=0.f; }

#pragma unroll 2
  for (int kc = 0; kc < 8; ++kc) {
    const int c0 = kc * 32 + g * 8;
    const float* wp = Wv + (size_t)(co0 + m) * 256 + c0;
    float4 a0 = *(const float4*)wp;
    float4 a1 = *(const float4*)(wp + 4);
    short8 af;
    af[0]=(short)f2bf(a0.x); af[1]=(short)f2bf(a0.y); af[2]=(short)f2bf(a0.z); af[3]=(short)f2bf(a0.w);
    af[4]=(short)f2bf(a1.x); af[5]=(short)f2bf(a1.y); af[6]=(short)f2bf(a1.z); af[7]=(short)f2bf(a1.w);
#pragma unroll
    for (int f = 0; f < 8; ++f) {
      const short8 bfr = *(const short8*)(xsf +
        ((((size_t)(b * 256 + (nT * 8 + f))) * 8 + kc) * 64 + l) * 8);
      acc[f] = __builtin_amdgcn_mfma_f32_16x16x32_bf16(af, bfr, acc[f], 0, 0, 0);
    }
  }
  float4 bvv = *(const float4*)(bv + co0 + g * 4);
  const float bvr[4] = {bvv.x, bvv.y, bvv.z, bvv.w};
#pragma unroll
  for (int f = 0; f < 8; ++f)
#pragma unroll
    for (int r = 0; r < 4; ++r) {
      const int co = co0 + g * 4 + r;
      const int n = n0 + f * 16 + m;
      vws[(((size_t)(b * 256 + co)) << 12) + n] = f2bf(acc[f][r] + bvr[r]);
    }
}

// ---------------- kernel 5: fused flash attention — PROVEN BEST (r19/r20/r24 config):
// 8 waves (512 thr), 128 queries/block, JBLK=128, grid 256 XCD-clustered.
// Wave w: S for queries w*16..; PV for channels w*32... Panel-P (0-conflict),
// P double-buffer + ONE barrier/iter, exp-no-max, V placement left to compiler.
#define P_PANEL  16384   // 128 rows x 128 B per panel, 2 panels per buffer
#define P_BUF    32768   // per-buffer P size
#define LDS_TOT  65536

__global__ __launch_bounds__(512, 2) void k_flash(
    const unsigned short* __restrict__ qh_ws, const unsigned short* __restrict__ ql_ws,
    const unsigned short* __restrict__ kh_ws, const unsigned short* __restrict__ v_ws,
    float* __restrict__ out0, unsigned short* __restrict__ pacc1,
    float* __restrict__ pl) {
  __shared__ char lds[LDS_TOT];
  const int bid = blockIdx.x;
  const int qt = bid >> 3;          // 0..31, 128 queries each
  const int b = (bid >> 1) & 3;
  const int jh = bid & 1;
  const int tid = threadIdx.x;
  const int w = __builtin_amdgcn_readfirstlane(tid >> 6);   // wave 0..7
  const int l = tid & 63;
  const int m = l & 15, g = l >> 4;

  const size_t qrow = (((size_t)b << 12) + (size_t)(qt * 128 + w * 16 + m)) * 32 + g * 8;
  const short8 qhf = *(const short8*)(qh_ws + qrow);
  const short8 qlf = *(const short8*)(ql_ws + qrow);

  f32x4 acc[8][2];
#pragma unroll
  for (int it = 0; it < 8; ++it)
#pragma unroll
    for (int ct = 0; ct < 2; ++ct) { acc[it][ct][0]=0.f; acc[it][ct][1]=0.f; acc[it][ct][2]=0.f; acc[it][ct][3]=0.f; }
  float lsum[4];
#pragma unroll
  for (int r = 0; r < 4; ++r) lsum[r] = 0.f;

  const int jbase = jh * 2048;
  for (int jt = 0; jt < 16; ++jt) {
    const int j128 = jbase + jt * 128;
    const int pb = jt & 1;
    char* Pb = lds + pb * P_BUF;
    short8 vbf[4][2];
#pragma unroll
    for (int ks = 0; ks < 4; ++ks)
#pragma unroll
      for (int ct = 0; ct < 2; ++ct)
        vbf[ks][ct] = *(const short8*)(v_ws +
          (((size_t)(b * 256 + w * 32 + ct * 16 + m)) << 12) + j128 + ks * 32 + g * 8);
    short8 khv[8];
#pragma unroll
    for (int t = 0; t < 8; ++t)
      khv[t] = *(const short8*)(kh_ws + (((size_t)b << 12) + (size_t)(j128 + t * 16 + m)) * 32 + g * 8);
    f32x4 sv[8];
#pragma unroll
    for (int t = 0; t < 8; ++t) {
      f32x4 z = {0.f, 0.f, 0.f, 0.f};
      f32x4 s0 = __builtin_amdgcn_mfma_f32_16x16x32_bf16(qhf, khv[t], z, 0, 0, 0);
      sv[t] = __builtin_amdgcn_mfma_f32_16x16x32_bf16(qlf, khv[t], s0, 0, 0, 0);
    }
#pragma unroll
    for (int t = 0; t < 8; ++t)
#pragma unroll
      for (int r = 0; r < 4; ++r) {
        const float p = exp2f(sv[t][r]);
        lsum[r] += p;
        const int row = w * 16 + g * 4 + r;
        const int cw2 = (t & 3) * 32 + 2 * m;
        *(unsigned short*)(Pb + (t >> 2) * P_PANEL + row * 128 + (cw2 ^ ((row & 7) << 4))) = f2bf(p);
      }
    __syncthreads();   // the ONLY barrier: P[pb] ready
#pragma unroll
    for (int ks = 0; ks < 4; ++ks) {
      short8 pa[8];
#pragma unroll
      for (int it = 0; it < 8; ++it) {
        const int row = it * 16 + m;
        pa[it] = *(const short8*)(Pb + (ks >> 1) * P_PANEL + row * 128 +
                                  (((ks & 1) * 64 + g * 16) ^ ((row & 7) << 4)));
      }
#pragma unroll
      for (int ct = 0; ct < 2; ++ct)
#pragma unroll
        for (int it = 0; it < 8; ++it)
          acc[it][ct] = __builtin_amdgcn_mfma_f32_16x16x32_bf16(pa[it], vbf[ks][ct], acc[it][ct], 0, 0, 0);
    }
    // no barrier B: next iter writes the OTHER P buffer (r14 safety argument)
  }
#pragma unroll
  for (int d = 1; d <= 8; d <<= 1)
#pragma unroll
    for (int r = 0; r < 4; ++r) lsum[r] += __shfl_xor(lsum[r], d);
  if (m == 0) {
#pragma unroll
    for (int r = 0; r < 4; ++r) {
      const int row = qt * 128 + w * 16 + g * 4 + r;
      pl[(size_t)jh * 16384 + ((size_t)b << 12) + row] = lsum[r];
    }
  }
  if (jh == 0) {
#pragma unroll
    for (int it = 0; it < 8; ++it)
#pragma unroll
      for (int ct = 0; ct < 2; ++ct) {
        const int c = w * 32 + ct * 16 + m;
        float4 o;
        o.x = acc[it][ct][0]; o.y = acc[it][ct][1]; o.z = acc[it][ct][2]; o.w = acc[it][ct][3];
        *(float4*)(out0 + (((size_t)(b * 256 + c)) << 12) + qt * 128 + it * 16 + g * 4) = o;
      }
  } else {
#pragma unroll
    for (int it = 0; it < 8; ++it)
#pragma unroll
      for (int ct = 0; ct < 2; ++ct) {
        const int c = w * 32 + ct * 16 + m;
        short4v o;
        o[0] = (short)f2bf(acc[it][ct][0]); o[1] = (short)f2bf(acc[it][ct][1]);
        o[2] = (short)f2bf(acc[it][ct][2]); o[3] = (short)f2bf(acc[it][ct][3]);
        *(short4v*)(pacc1 + (((size_t)(b * 256 + c)) << 12) + qt * 128 + it * 16 + g * 4) = o;
      }
  }
}

// ---------------- kernel 6: combine the two j-halves (in-place on out) ----------------
__global__ __launch_bounds__(256) void k_combine(float* o, const unsigned short* __restrict__ pacc1,
                                                 const float* __restrict__ pl) {
  const int b = blockIdx.y;
  const int n = blockIdx.x * 64 + (threadIdx.x & 63);
  const int c0 = (threadIdx.x >> 6) * 64;
  const size_t mi = ((size_t)b << 12) + n;
  const float rl = 1.0f / (pl[mi] + pl[16384 + mi]);
#pragma unroll 4
  for (int ci = 0; ci < 64; ++ci) {
    const size_t a = (((size_t)(b * 256 + c0 + ci)) << 12) + n;
    o[a] = (o[a] + bf2f(pacc1[a])) * rl;
  }
}

// ---------------- launch ----------------
extern "C" void kernel_launch(void* const* d_in, const int* in_sizes, int n_in,
                              void* d_out, int out_size, void* d_ws, size_t ws_size,
                              hipStream_t stream) {
  (void)in_sizes; (void)n_in; (void)out_size; (void)ws_size;
  const float* input     = (const float*)d_in[0];
  const float* structure = (const float*)d_in[1];
  const float* style     = (const float*)d_in[2];
  const float* Wq = (const float*)d_in[3];
  const float* bq = (const float*)d_in[4];
  const float* Wk = (const float*)d_in[5];
  const float* bk = (const float*)d_in[6];
  const float* Wv = (const float*)d_in[7];
  const float* bv = (const float*)d_in[8];
  float* out = (float*)d_out;
  char* ws = (char*)d_ws;

  // ws layout — proven extents: total 20,250,624 B
  float* wt           = (float*)(ws);
  unsigned short* qh  = (unsigned short*)(ws + 65536);
  unsigned short* ql  = (unsigned short*)(ws + 65536 + 1048576);
  unsigned short* kh  = (unsigned short*)(ws + 65536 + 2097152);
  unsigned short* vw  = (unsigned short*)(ws + 65536 + 3145728);               // row-major V
  unsigned short* xsf = (unsigned short*)(ws + 65536 + 3145728 + 8388608);     // fragment-order
  unsigned short* pacc1 = xsf;  // aliases xsf (dead after k_vgemm; stream-ordered)
  float* pl           = (float*)(ws + 20119552);

  k_wtrans<<<dim3(1), dim3(256), 0, stream>>>(Wq, Wk, wt);
  k_projcast<<<dim3(512), dim3(256), 0, stream>>>(input, structure, wt, bq, bk,
                                                  qh, ql, kh, style, xsf);
  k_vgemm<<<dim3(32, 4, 4), dim3(256), 0, stream>>>(xsf, Wv, bv, vw);
  k_flash<<<dim3(256), dim3(512), 0, stream>>>(qh, ql, kh, vw, out, pacc1, pl);
  k_combine<<<dim3(64, 4), dim3(256), 0, stream>>>(out, pacc1, pl);
}